// Round 1
// baseline (11274.539 us; speedup 1.0000x reference)
//
#include <hip/hip_runtime.h>

#define N_NODES 50000
#define N_EDGES 800000
#define N_REL   8

// ---------------- utility kernels ----------------

__global__ void zero_f32(float* __restrict__ p, int n) {
    int i = blockIdx.x * blockDim.x + threadIdx.x;
    if (i < n) p[i] = 0.0f;
}

__global__ void count_edges(const int* __restrict__ dst, const int* __restrict__ et,
                            float* __restrict__ cnt) {
    int e = blockIdx.x * blockDim.x + threadIdx.x;
    if (e < N_EDGES) atomicAdd(&cnt[et[e] * N_NODES + dst[e]], 1.0f);
}

__global__ void inv_counts(float* __restrict__ cnt, int n) {
    int i = blockIdx.x * blockDim.x + threadIdx.x;
    if (i < n) cnt[i] = 1.0f / fmaxf(cnt[i], 1.0f);
}

__global__ void relu_inplace(float* __restrict__ p, int n) {
    int i = blockIdx.x * blockDim.x + threadIdx.x;
    if (i < n) p[i] = fmaxf(p[i], 0.0f);
}

// ---------------- fp32 tiled GEMM: C[M,O] = A[M,K] @ B[K,O] (+bias) ----------------
// BM=BN=64, BK=16, 256 threads, 4x4 micro-tile per thread.
template<bool ADD_BIAS>
__global__ void gemm_kernel(const float* __restrict__ A, const float* __restrict__ B,
                            const float* __restrict__ bias, float* __restrict__ C,
                            int M, int K, int O) {
    __shared__ float As[16][65];   // As[k][m], +1 pad
    __shared__ float Bs[16][64];   // Bs[k][n]
    const int t   = threadIdx.x;
    const int tx  = t & 15;        // col group
    const int ty  = t >> 4;        // row group
    const int row0 = blockIdx.x * 64;
    const int col0 = blockIdx.y * 64;
    // A-tile load mapping: 64 rows x 16 k, float4 per thread
    const int am  = t >> 2;             // 0..63
    const int akg = (t & 3) << 2;       // 0,4,8,12
    // B-tile load mapping: 16 k x 64 cols, float4 per thread
    const int bk  = t >> 4;             // 0..15
    const int bcg = (t & 15) << 2;      // 0..60

    float acc[4][4] = {};

    for (int k0 = 0; k0 < K; k0 += 16) {
        float4 av = make_float4(0.f, 0.f, 0.f, 0.f);
        if (row0 + am < M)
            av = *(const float4*)(A + (size_t)(row0 + am) * K + k0 + akg);
        float4 bv = *(const float4*)(B + (size_t)(k0 + bk) * O + col0 + bcg);
        __syncthreads();   // previous iteration done reading LDS
        As[akg + 0][am] = av.x;
        As[akg + 1][am] = av.y;
        As[akg + 2][am] = av.z;
        As[akg + 3][am] = av.w;
        *(float4*)(&Bs[bk][bcg]) = bv;
        __syncthreads();
        #pragma unroll
        for (int k = 0; k < 16; ++k) {
            float a[4], b[4];
            #pragma unroll
            for (int i = 0; i < 4; ++i) a[i] = As[k][ty * 4 + i];
            #pragma unroll
            for (int j = 0; j < 4; ++j) b[j] = Bs[k][tx * 4 + j];
            #pragma unroll
            for (int i = 0; i < 4; ++i)
                #pragma unroll
                for (int j = 0; j < 4; ++j)
                    acc[i][j] += a[i] * b[j];
        }
    }

    #pragma unroll
    for (int i = 0; i < 4; ++i) {
        int row = row0 + ty * 4 + i;
        if (row < M) {
            float4 v = make_float4(acc[i][0], acc[i][1], acc[i][2], acc[i][3]);
            if (ADD_BIAS) {
                v.x += bias[col0 + tx * 4 + 0];
                v.y += bias[col0 + tx * 4 + 1];
                v.z += bias[col0 + tx * 4 + 2];
                v.w += bias[col0 + tx * 4 + 3];
            }
            *(float4*)(C + (size_t)row * O + col0 + tx * 4) = v;
        }
    }
}

// ---------------- per-edge scatter: out[dst] += Y[src] * inv_cnt[r,dst] ----------------
// One wave (64 lanes) per edge; block of 256 handles 4 edges.
__global__ void scatter_kernel(const float* __restrict__ Y, const int* __restrict__ src,
                               const int* __restrict__ dst, const int* __restrict__ et,
                               const float* __restrict__ inv_cnt, float* __restrict__ out,
                               int rel, int O) {
    int e = blockIdx.x * 4 + (threadIdx.x >> 6);
    if (e >= N_EDGES) return;
    if (et[e] != rel) return;
    int lane = threadIdx.x & 63;
    int s = src[e], d = dst[e];
    float inv = inv_cnt[rel * N_NODES + d];
    if (O == 256) {
        const float4 v = *(const float4*)(Y + (size_t)s * 256 + lane * 4);
        float* o = out + (size_t)d * 256 + lane * 4;
        atomicAdd(o + 0, v.x * inv);
        atomicAdd(o + 1, v.y * inv);
        atomicAdd(o + 2, v.z * inv);
        atomicAdd(o + 3, v.w * inv);
    } else {  // O == 64
        float v = Y[(size_t)s * 64 + lane];
        atomicAdd(out + (size_t)d * 64 + lane, v * inv);
    }
}

// ---------------- host-side layer driver ----------------

static void run_layer(const float* hin, int I, int O,
                      const float* W, const float* root, const float* bias,
                      float* Y, float* out,
                      const int* src, const int* dst, const int* et,
                      const float* inv_cnt, bool relu, hipStream_t stream) {
    dim3 blk(256);
    dim3 grd((N_NODES + 63) / 64, O / 64);
    // out = hin @ root + bias
    gemm_kernel<true><<<grd, blk, 0, stream>>>(hin, root, bias, out, N_NODES, I, O);
    for (int r = 0; r < N_REL; ++r) {
        // Y = hin @ W_r
        gemm_kernel<false><<<grd, blk, 0, stream>>>(hin, W + (size_t)r * I * O, nullptr, Y,
                                                    N_NODES, I, O);
        // out[dst] += Y[src] * inv_cnt[r,dst]  over edges of type r
        scatter_kernel<<<(N_EDGES + 3) / 4, 256, 0, stream>>>(Y, src, dst, et, inv_cnt, out, r, O);
    }
    if (relu) {
        int n = N_NODES * O;
        relu_inplace<<<(n + 255) / 256, 256, 0, stream>>>(out, n);
    }
}

extern "C" void kernel_launch(void* const* d_in, const int* in_sizes, int n_in,
                              void* d_out, int out_size, void* d_ws, size_t ws_size,
                              hipStream_t stream) {
    const float* x  = (const float*)d_in[0];
    const int*   ei = (const int*)d_in[1];   // [2, E] int32: row 0 = src, row 1 = dst
    const int*   et = (const int*)d_in[2];   // [E]
    const float* W1 = (const float*)d_in[3];
    const float* r1 = (const float*)d_in[4];
    const float* b1 = (const float*)d_in[5];
    const float* W2 = (const float*)d_in[6];
    const float* r2 = (const float*)d_in[7];
    const float* b2 = (const float*)d_in[8];
    const float* W3 = (const float*)d_in[9];
    const float* r3 = (const float*)d_in[10];
    const float* b3 = (const float*)d_in[11];
    const float* W4 = (const float*)d_in[12];
    const float* r4 = (const float*)d_in[13];
    const float* b4 = (const float*)d_in[14];
    const int* src = ei;
    const int* dst = ei + N_EDGES;

    // workspace layout (fp32): inv_cnt[R*N] | h0[N*256] | h1[N*256] | Y[N*256]  ~= 155 MB
    float* inv_cnt = (float*)d_ws;
    float* h0 = inv_cnt + (size_t)N_REL * N_NODES;
    float* h1 = h0 + (size_t)N_NODES * 256;
    float* Y  = h1 + (size_t)N_NODES * 256;

    // per-(relation,dst) mean normalizers — layer-invariant, once per call
    int ncnt = N_REL * N_NODES;
    zero_f32<<<(ncnt + 255) / 256, 256, 0, stream>>>(inv_cnt, ncnt);
    count_edges<<<(N_EDGES + 255) / 256, 256, 0, stream>>>(dst, et, inv_cnt);
    inv_counts<<<(ncnt + 255) / 256, 256, 0, stream>>>(inv_cnt, ncnt);

    run_layer(x,  128, 256, W1, r1, b1, Y, h0, src, dst, et, inv_cnt, true,  stream);
    run_layer(h0, 256, 256, W2, r2, b2, Y, h1, src, dst, et, inv_cnt, true,  stream);
    run_layer(h1, 256, 256, W3, r3, b3, Y, h0, src, dst, et, inv_cnt, true,  stream);
    run_layer(h0, 256, 64,  W4, r4, b4, Y, (float*)d_out, src, dst, et, inv_cnt, false, stream);
}

// Round 2
// 1882.064 us; speedup vs baseline: 5.9905x; 5.9905x over previous
//
#include <hip/hip_runtime.h>

#define N_NODES 50000
#define N_EDGES 800000
#define N_REL   8
#define NSEG    (N_REL * N_NODES)      // 400000
#define SCAN_NB 391                    // ceil(400000 / 1024)

typedef short bf16x8 __attribute__((ext_vector_type(8)));
typedef float f32x4  __attribute__((ext_vector_type(4)));

__device__ __forceinline__ ushort f2bf(float f) {
    union { float f; unsigned u; } c; c.f = f;
    unsigned u = c.u + 0x7fffu + ((c.u >> 16) & 1u);   // round-to-nearest-even
    return (ushort)(u >> 16);
}

// ---------------- edge preprocessing: counting sort by (rel*N + dst) ----------------

__global__ void count_edges(const int* __restrict__ dst, const int* __restrict__ et,
                            int* __restrict__ cnt) {
    int e = blockIdx.x * 256 + threadIdx.x;
    if (e < N_EDGES) atomicAdd(&cnt[et[e] * N_NODES + dst[e]], 1);
}

__global__ __launch_bounds__(256) void scan_pass1(const int* __restrict__ cnt,
                                                  int* __restrict__ sums) {
    __shared__ int sc[256];
    int b = blockIdx.x, t = threadIdx.x;
    int base = b * 1024 + t * 4;
    int v = 0;
    #pragma unroll
    for (int i = 0; i < 4; ++i) { int idx = base + i; if (idx < NSEG) v += cnt[idx]; }
    sc[t] = v; __syncthreads();
    for (int off = 1; off < 256; off <<= 1) {
        int x = (t >= off) ? sc[t - off] : 0;
        __syncthreads();
        sc[t] += x;
        __syncthreads();
    }
    if (t == 255) sums[b] = sc[255];
}

__global__ __launch_bounds__(512) void scan_pass2(int* __restrict__ sums, int nb) {
    __shared__ int sc[512];
    int t = threadIdx.x;
    int v = (t < nb) ? sums[t] : 0;
    sc[t] = v; __syncthreads();
    for (int off = 1; off < 512; off <<= 1) {
        int x = (t >= off) ? sc[t - off] : 0;
        __syncthreads();
        sc[t] += x;
        __syncthreads();
    }
    if (t < nb) sums[t] = sc[t] - v;     // exclusive
}

__global__ __launch_bounds__(256) void scan_pass3(const int* __restrict__ cnt,
                                                  const int* __restrict__ sums,
                                                  int* __restrict__ row_ptr) {
    __shared__ int sc[256];
    int b = blockIdx.x, t = threadIdx.x;
    int base = b * 1024 + t * 4;
    int e[4]; int v = 0;
    #pragma unroll
    for (int i = 0; i < 4; ++i) { int idx = base + i; e[i] = (idx < NSEG) ? cnt[idx] : 0; v += e[i]; }
    sc[t] = v; __syncthreads();
    for (int off = 1; off < 256; off <<= 1) {
        int x = (t >= off) ? sc[t - off] : 0;
        __syncthreads();
        sc[t] += x;
        __syncthreads();
    }
    int run = sums[b] + (sc[t] - v);
    #pragma unroll
    for (int i = 0; i < 4; ++i) {
        int idx = base + i;
        if (idx < NSEG) row_ptr[idx] = run;
        run += e[i];
    }
    if (b == 0 && t == 0) row_ptr[NSEG] = N_EDGES;
}

__global__ void place_edges(const int* __restrict__ src, const int* __restrict__ dst,
                            const int* __restrict__ et, const int* __restrict__ row_ptr,
                            int* __restrict__ cursor, int* __restrict__ sorted_src) {
    int e = blockIdx.x * 256 + threadIdx.x;
    if (e >= N_EDGES) return;
    int key = et[e] * N_NODES + dst[e];
    int pos = row_ptr[key] + atomicAdd(&cursor[key], 1);
    sorted_src[pos] = src[e];
}

// ---------------- dtype conversion ----------------

// W [R,I,O] fp32 -> WT [R,O,I] bf16 (transposed per relation, for GEMM B^T operand)
__global__ void convert_wT(const float* __restrict__ W, ushort* __restrict__ WT,
                           int R_, int I, int O) {
    int idx = blockIdx.x * 256 + threadIdx.x;
    if (idx >= R_ * I * O) return;
    int o = idx % O;
    int rem = idx / O;
    int i = rem % I;
    int r = rem / I;
    WT[((size_t)r * O + o) * I + i] = f2bf(W[idx]);
}

template<bool RELU>
__global__ void f32_to_bf16(const float* __restrict__ in, ushort* __restrict__ out, int n4) {
    int i = blockIdx.x * 256 + threadIdx.x;
    if (i >= n4) return;
    float4 v = ((const float4*)in)[i];
    if (RELU) {
        v.x = fmaxf(v.x, 0.f); v.y = fmaxf(v.y, 0.f);
        v.z = fmaxf(v.z, 0.f); v.w = fmaxf(v.w, 0.f);
    }
    ushort4 s; s.x = f2bf(v.x); s.y = f2bf(v.y); s.z = f2bf(v.z); s.w = f2bf(v.w);
    ((ushort4*)out)[i] = s;
}

// ---------------- bf16 MFMA GEMM: C[M,O] = A[M,K] @ BT[O,K]^T (+bias) ----------------
// 64x64 tile, BK=32, 256 threads (4 waves), each wave a 32x32 quadrant via
// 4x mfma_f32_16x16x32_bf16. A and BT both bf16 row-major-in-K -> identical staging.
template<bool BIAS, bool OUT_BF16>
__global__ __launch_bounds__(256)
void gemm_mfma(const ushort* __restrict__ Ab, const ushort* __restrict__ BT,
               const float* __restrict__ bias, void* __restrict__ Cv,
               int M, int K, int O) {
    __shared__ ushort As[64][56];   // row stride 112B: 16B-aligned, bank-friendly
    __shared__ ushort Bs[64][56];
    const int t = threadIdx.x;
    const int row0 = blockIdx.x * 64;
    const int col0 = blockIdx.y * 64;
    const int lane = t & 63;
    const int w = t >> 6;
    const int q = lane >> 4;        // quad 0..3
    const int l16 = lane & 15;
    const int wm = (w & 1) * 32;    // wave's 32x32 quadrant
    const int wn = (w >> 1) * 32;

    // staging: thread t copies one 16B chunk of A and one of B per k-step
    const int ar = t >> 2;            // 0..63
    const int ak = (t & 3) << 3;      // 0,8,16,24
    const bool ga = (row0 + ar) < M;
    const ushort* Arow = Ab + (size_t)(row0 + ar) * K + ak;
    const ushort* Brow = BT + (size_t)(col0 + ar) * K + ak;

    f32x4 acc00 = {0.f,0.f,0.f,0.f}, acc01 = {0.f,0.f,0.f,0.f};
    f32x4 acc10 = {0.f,0.f,0.f,0.f}, acc11 = {0.f,0.f,0.f,0.f};
    const uint4 zero4 = make_uint4(0u, 0u, 0u, 0u);

    for (int k0 = 0; k0 < K; k0 += 32) {
        uint4 av = ga ? *(const uint4*)(Arow + k0) : zero4;
        uint4 bv = *(const uint4*)(Brow + k0);
        __syncthreads();
        *(uint4*)&As[ar][ak] = av;
        *(uint4*)&Bs[ar][ak] = bv;
        __syncthreads();
        bf16x8 af0 = *(const bf16x8*)&As[wm + l16][q * 8];
        bf16x8 af1 = *(const bf16x8*)&As[wm + 16 + l16][q * 8];
        bf16x8 bf0 = *(const bf16x8*)&Bs[wn + l16][q * 8];
        bf16x8 bf1 = *(const bf16x8*)&Bs[wn + 16 + l16][q * 8];
        acc00 = __builtin_amdgcn_mfma_f32_16x16x32_bf16(af0, bf0, acc00, 0, 0, 0);
        acc01 = __builtin_amdgcn_mfma_f32_16x16x32_bf16(af0, bf1, acc01, 0, 0, 0);
        acc10 = __builtin_amdgcn_mfma_f32_16x16x32_bf16(af1, bf0, acc10, 0, 0, 0);
        acc11 = __builtin_amdgcn_mfma_f32_16x16x32_bf16(af1, bf1, acc11, 0, 0, 0);
    }

    // epilogue: D mapping col = l16, row = q*4 + reg  (verified gfx950 layout)
    f32x4 accs[2][2] = {{acc00, acc01}, {acc10, acc11}};
    #pragma unroll
    for (int j = 0; j < 2; ++j) {
        int gcol = col0 + wn + j * 16 + l16;
        float bvs = BIAS ? bias[gcol] : 0.0f;
        #pragma unroll
        for (int i = 0; i < 2; ++i) {
            #pragma unroll
            for (int reg = 0; reg < 4; ++reg) {
                int grow = row0 + wm + i * 16 + q * 4 + reg;
                if (grow < M) {
                    float v = accs[i][j][reg] + bvs;
                    if (OUT_BF16) ((ushort*)Cv)[(size_t)grow * O + gcol] = f2bf(v);
                    else          ((float*)Cv)[(size_t)grow * O + gcol] = v;
                }
            }
        }
    }
}

// ---------------- segment gather: out[d] += mean_{e in seg(r,d)} Y[src_e] ----------------
// Thread owns (dst node, 8-column chunk). No atomics: one writer per (d, chunk) per launch.
template<int O>
__global__ __launch_bounds__(256)
void gather_kernel(const ushort* __restrict__ Yb, const int* __restrict__ row_ptr,
                   const int* __restrict__ sorted_src, float* __restrict__ out, int rel) {
    constexpr int TPN = O / 8;                    // threads per node
    int d = blockIdx.x * (256 / TPN) + threadIdx.x / TPN;
    if (d >= N_NODES) return;
    int c0 = (threadIdx.x % TPN) * 8;
    int base = rel * N_NODES + d;
    int s0 = row_ptr[base], s1 = row_ptr[base + 1];
    if (s1 <= s0) return;
    float sum[8] = {0.f,0.f,0.f,0.f,0.f,0.f,0.f,0.f};
    for (int j = s0; j < s1; ++j) {
        int s = sorted_src[j];
        uint4 v = *(const uint4*)(Yb + (size_t)s * O + c0);   // 8 bf16
        unsigned u[4] = {v.x, v.y, v.z, v.w};
        #pragma unroll
        for (int k = 0; k < 4; ++k) {
            sum[2 * k]     += __uint_as_float(u[k] << 16);
            sum[2 * k + 1] += __uint_as_float(u[k] & 0xffff0000u);
        }
    }
    float inv = 1.0f / (float)(s1 - s0);
    float* op = out + (size_t)d * O + c0;
    float4 o0 = *(float4*)op, o1 = *(float4*)(op + 4);
    o0.x += sum[0] * inv; o0.y += sum[1] * inv; o0.z += sum[2] * inv; o0.w += sum[3] * inv;
    o1.x += sum[4] * inv; o1.y += sum[5] * inv; o1.z += sum[6] * inv; o1.w += sum[7] * inv;
    *(float4*)op = o0; *(float4*)(op + 4) = o1;
}

// ---------------- host-side drivers ----------------

static void launch_gemm(const ushort* Ab, const ushort* BT, const float* bias, void* C,
                        int M, int K, int O, bool root, hipStream_t st) {
    dim3 g((M + 63) / 64, O / 64), b(256);
    if (root) gemm_mfma<true, false><<<g, b, 0, st>>>(Ab, BT, bias, C, M, K, O);
    else      gemm_mfma<false, true><<<g, b, 0, st>>>(Ab, BT, nullptr, C, M, K, O);
}

static void rgcn_layer(const ushort* hb, int I, int O, const ushort* WT, const ushort* rootT,
                       const float* bias, ushort* Yb, float* out,
                       const int* row_ptr, const int* sorted_src, hipStream_t st) {
    launch_gemm(hb, rootT, bias, out, N_NODES, I, O, true, st);   // out = h@root + bias
    for (int r = 0; r < N_REL; ++r) {
        launch_gemm(hb, WT + (size_t)r * O * I, nullptr, Yb, N_NODES, I, O, false, st);
        if (O == 256)
            gather_kernel<256><<<(N_NODES * 32 + 255) / 256, 256, 0, st>>>(Yb, row_ptr, sorted_src, out, r);
        else
            gather_kernel<64><<<(N_NODES * 8 + 255) / 256, 256, 0, st>>>(Yb, row_ptr, sorted_src, out, r);
    }
}

extern "C" void kernel_launch(void* const* d_in, const int* in_sizes, int n_in,
                              void* d_out, int out_size, void* d_ws, size_t ws_size,
                              hipStream_t stream) {
    const float* x  = (const float*)d_in[0];
    const int*   ei = (const int*)d_in[1];
    const int*   et = (const int*)d_in[2];
    const float* W1 = (const float*)d_in[3];
    const float* r1 = (const float*)d_in[4];
    const float* b1 = (const float*)d_in[5];
    const float* W2 = (const float*)d_in[6];
    const float* r2 = (const float*)d_in[7];
    const float* b2 = (const float*)d_in[8];
    const float* W3 = (const float*)d_in[9];
    const float* r3 = (const float*)d_in[10];
    const float* b3 = (const float*)d_in[11];
    const float* W4 = (const float*)d_in[12];
    const float* r4 = (const float*)d_in[13];
    const float* b4 = (const float*)d_in[14];
    const int* src = ei;
    const int* dst = ei + N_EDGES;

    // ---- workspace carve-up (~114 MB; 155 MB proven available in round 1) ----
    char* ws = (char*)d_ws;
    size_t off = 0;
    auto take = [&](size_t bytes) -> char* {
        char* p = ws + off;
        off = (off + bytes + 15) & ~(size_t)15;
        return p;
    };
    int* cnt        = (int*)take((size_t)NSEG * 4);
    int* cursor     = (int*)take((size_t)NSEG * 4);
    int* row_ptr    = (int*)take((size_t)(NSEG + 1) * 4);
    int* sums       = (int*)take(512 * 4);
    int* sorted_src = (int*)take((size_t)N_EDGES * 4);
    ushort* w1T = (ushort*)take((size_t)8 * 128 * 256 * 2);
    ushort* r1T = (ushort*)take((size_t)128 * 256 * 2);
    ushort* w2T = (ushort*)take((size_t)8 * 256 * 256 * 2);
    ushort* r2T = (ushort*)take((size_t)256 * 256 * 2);
    ushort* w3T = (ushort*)take((size_t)8 * 256 * 256 * 2);
    ushort* r3T = (ushort*)take((size_t)256 * 256 * 2);
    ushort* w4T = (ushort*)take((size_t)8 * 256 * 64 * 2);
    ushort* r4T = (ushort*)take((size_t)256 * 64 * 2);
    float*  hf  = (float*)take((size_t)N_NODES * 256 * 4);   // fp32 layer accumulator
    ushort* hb  = (ushort*)take((size_t)N_NODES * 256 * 2);  // bf16 layer input
    ushort* Yb  = (ushort*)take((size_t)N_NODES * 256 * 2);  // bf16 transformed feats

    // ---- edge preprocessing (per call; edges identical across layers) ----
    hipMemsetAsync(cnt, 0, (size_t)NSEG * 4, stream);
    hipMemsetAsync(cursor, 0, (size_t)NSEG * 4, stream);
    count_edges<<<(N_EDGES + 255) / 256, 256, 0, stream>>>(dst, et, cnt);
    scan_pass1<<<SCAN_NB, 256, 0, stream>>>(cnt, sums);
    scan_pass2<<<1, 512, 0, stream>>>(sums, SCAN_NB);
    scan_pass3<<<SCAN_NB, 256, 0, stream>>>(cnt, sums, row_ptr);
    place_edges<<<(N_EDGES + 255) / 256, 256, 0, stream>>>(src, dst, et, row_ptr, cursor, sorted_src);

    // ---- weight conversion + transpose (per call) ----
    convert_wT<<<(8 * 128 * 256 + 255) / 256, 256, 0, stream>>>(W1, w1T, 8, 128, 256);
    convert_wT<<<(128 * 256 + 255) / 256, 256, 0, stream>>>(r1, r1T, 1, 128, 256);
    convert_wT<<<(8 * 256 * 256 + 255) / 256, 256, 0, stream>>>(W2, w2T, 8, 256, 256);
    convert_wT<<<(256 * 256 + 255) / 256, 256, 0, stream>>>(r2, r2T, 1, 256, 256);
    convert_wT<<<(8 * 256 * 256 + 255) / 256, 256, 0, stream>>>(W3, w3T, 8, 256, 256);
    convert_wT<<<(256 * 256 + 255) / 256, 256, 0, stream>>>(r3, r3T, 1, 256, 256);
    convert_wT<<<(8 * 256 * 64 + 255) / 256, 256, 0, stream>>>(W4, w4T, 8, 256, 64);
    convert_wT<<<(256 * 64 + 255) / 256, 256, 0, stream>>>(r4, r4T, 1, 256, 64);

    // ---- 4 RGCN layers; ReLU fused into the fp32->bf16 conversion ----
    f32_to_bf16<false><<<(N_NODES * 128 / 4 + 255) / 256, 256, 0, stream>>>(x, hb, N_NODES * 128 / 4);
    rgcn_layer(hb, 128, 256, w1T, r1T, b1, Yb, hf, row_ptr, sorted_src, stream);

    f32_to_bf16<true><<<(N_NODES * 256 / 4 + 255) / 256, 256, 0, stream>>>(hf, hb, N_NODES * 256 / 4);
    rgcn_layer(hb, 256, 256, w2T, r2T, b2, Yb, hf, row_ptr, sorted_src, stream);

    f32_to_bf16<true><<<(N_NODES * 256 / 4 + 255) / 256, 256, 0, stream>>>(hf, hb, N_NODES * 256 / 4);
    rgcn_layer(hb, 256, 256, w3T, r3T, b3, Yb, hf, row_ptr, sorted_src, stream);

    f32_to_bf16<true><<<(N_NODES * 256 / 4 + 255) / 256, 256, 0, stream>>>(hf, hb, N_NODES * 256 / 4);
    rgcn_layer(hb, 256, 64, w4T, r4T, b4, Yb, (float*)d_out, row_ptr, sorted_src, stream);
}

// Round 3
// 823.970 us; speedup vs baseline: 13.6832x; 2.2841x over previous
//
#include <hip/hip_runtime.h>

#define N_NODES 50000
#define N_PAD   50048          // 391 * 128
#define N_EDGES 800000
#define N_REL   8
#define NSEG    (N_REL * N_NODES)      // 400000
#define SCAN_NB 391                    // ceil(NSEG / 1024)

typedef short bf16x8 __attribute__((ext_vector_type(8)));
typedef float f32x4  __attribute__((ext_vector_type(4)));

__device__ __forceinline__ ushort f2bf(float f) {
    union { float f; unsigned u; } c; c.f = f;
    unsigned u = c.u + 0x7fffu + ((c.u >> 16) & 1u);   // RNE
    return (ushort)(u >> 16);
}
__device__ __forceinline__ void add8(float* s, uint4 v) {
    unsigned u[4] = {v.x, v.y, v.z, v.w};
    #pragma unroll
    for (int k = 0; k < 4; ++k) {
        s[2 * k]     += __uint_as_float(u[k] << 16);
        s[2 * k + 1] += __uint_as_float(u[k] & 0xffff0000u);
    }
}
__device__ __forceinline__ void async16(const ushort* g, ushort* l) {
    __builtin_amdgcn_global_load_lds((const __attribute__((address_space(1))) void*)g,
                                     (__attribute__((address_space(3))) void*)l, 16, 0, 0);
}

// ---------------- edge preprocessing: counting sort by (rel*N + dst) ----------------

__global__ void count_edges(const int* __restrict__ dst, const int* __restrict__ et,
                            int* __restrict__ cnt) {
    int e = blockIdx.x * 256 + threadIdx.x;
    if (e < N_EDGES) atomicAdd(&cnt[et[e] * N_NODES + dst[e]], 1);
}

__global__ __launch_bounds__(256) void scan_pass1(const int* __restrict__ cnt,
                                                  int* __restrict__ sums) {
    __shared__ int sc[256];
    int b = blockIdx.x, t = threadIdx.x;
    int base = b * 1024 + t * 4;
    int v = 0;
    #pragma unroll
    for (int i = 0; i < 4; ++i) { int idx = base + i; if (idx < NSEG) v += cnt[idx]; }
    sc[t] = v; __syncthreads();
    for (int off = 1; off < 256; off <<= 1) {
        int x = (t >= off) ? sc[t - off] : 0;
        __syncthreads(); sc[t] += x; __syncthreads();
    }
    if (t == 255) sums[b] = sc[255];
}

__global__ __launch_bounds__(512) void scan_pass2(int* __restrict__ sums, int nb) {
    __shared__ int sc[512];
    int t = threadIdx.x;
    int v = (t < nb) ? sums[t] : 0;
    sc[t] = v; __syncthreads();
    for (int off = 1; off < 512; off <<= 1) {
        int x = (t >= off) ? sc[t - off] : 0;
        __syncthreads(); sc[t] += x; __syncthreads();
    }
    if (t < nb) sums[t] = sc[t] - v;     // exclusive
}

__global__ __launch_bounds__(256) void scan_pass3(const int* __restrict__ cnt,
                                                  const int* __restrict__ sums,
                                                  int* __restrict__ row_ptr) {
    __shared__ int sc[256];
    int b = blockIdx.x, t = threadIdx.x;
    int base = b * 1024 + t * 4;
    int e[4]; int v = 0;
    #pragma unroll
    for (int i = 0; i < 4; ++i) { int idx = base + i; e[i] = (idx < NSEG) ? cnt[idx] : 0; v += e[i]; }
    sc[t] = v; __syncthreads();
    for (int off = 1; off < 256; off <<= 1) {
        int x = (t >= off) ? sc[t - off] : 0;
        __syncthreads(); sc[t] += x; __syncthreads();
    }
    int run = sums[b] + (sc[t] - v);
    #pragma unroll
    for (int i = 0; i < 4; ++i) {
        int idx = base + i;
        if (idx < NSEG) row_ptr[idx] = run;
        run += e[i];
    }
    if (b == 0 && t == 0) row_ptr[NSEG] = N_EDGES;
}

// cnt doubles as the placement cursor (atomicSub); cnt is dead afterwards.
__global__ void place_edges(const int* __restrict__ src, const int* __restrict__ dst,
                            const int* __restrict__ et, const int* __restrict__ row_ptr,
                            int* __restrict__ cnt, int* __restrict__ sorted_src) {
    int e = blockIdx.x * 256 + threadIdx.x;
    if (e >= N_EDGES) return;
    int key = et[e] * N_NODES + dst[e];
    int old = atomicSub(&cnt[key], 1);
    sorted_src[row_ptr[key] + old - 1] = src[e];
}

// ---------------- weight pack: [W(R,I,O) | root(I,O) | zero-pad] -> BT[NPAD][I] bf16 ----------------

__global__ void convert_weights(const float* __restrict__ W, const float* __restrict__ root,
                                ushort* __restrict__ BT, int I, int O, int NPAD) {
    int idx = blockIdx.x * 256 + threadIdx.x;
    if (idx >= NPAD * I) return;
    int col = idx / I, i = idx % I;
    float v = 0.0f;
    if (col < N_REL * O) {
        int r = col / O, o = col % O;
        v = W[((size_t)r * I + i) * O + o];
    } else if (col < (N_REL + 1) * O) {
        v = root[(size_t)i * O + (col - N_REL * O)];
    }
    BT[idx] = f2bf(v);
}

__global__ void f32_to_bf16(const float* __restrict__ in, ushort* __restrict__ out, int n4) {
    int i = blockIdx.x * 256 + threadIdx.x;
    if (i >= n4) return;
    float4 v = ((const float4*)in)[i];
    ushort4 s; s.x = f2bf(v.x); s.y = f2bf(v.y); s.z = f2bf(v.z); s.w = f2bf(v.w);
    ((ushort4*)out)[i] = s;
}

// ---------------- bf16 MFMA GEMM, m97 structure: 128x128 tile, BK=32, global_load_lds ----------------
// A [N_PAD][K] bf16, BT [NW_pad][K] bf16, Y [N_PAD][NW] bf16. No bounds checks (padded).
template<int K>
__global__ __launch_bounds__(256)
void gemm_mfma(const ushort* __restrict__ A, const ushort* __restrict__ BT,
               ushort* __restrict__ Y, int NW) {
    __shared__ ushort As[128 * 32];   // 8 KB, rows of 64B, NO padding (global_load_lds layout)
    __shared__ ushort Bs[128 * 32];
    const int t = threadIdx.x;
    const int lane = t & 63;
    const int w = t >> 6;
    const int l16 = lane & 15, q = lane >> 4;
    const int wm = (w & 1) * 64, wn = (w >> 1) * 64;
    const int row0 = blockIdx.x * 128;
    const int col0 = blockIdx.y * 128;

    // staging: chunk c (0..511) = 16B; row = c>>2, kcol = (c&3)*8. Wave w handles
    // chunks [w*64, w*64+64) and [(w+4)*64, ...): LDS dst = wave-uniform base + lane*16.
    const int c0i = w * 64 + lane;
    const int c1i = c0i + 256;
    const size_t ga0 = (size_t)(c0i >> 2) * K + (size_t)(c0i & 3) * 8;
    const size_t ga1 = (size_t)(c1i >> 2) * K + (size_t)(c1i & 3) * 8;
    const ushort* Ab = A + (size_t)row0 * K;
    const ushort* Bb = BT + (size_t)col0 * K;
    ushort* lA0 = &As[w * 512];
    ushort* lA1 = &As[(w + 4) * 512];
    ushort* lB0 = &Bs[w * 512];
    ushort* lB1 = &Bs[(w + 4) * 512];

    f32x4 acc[4][4] = {};

    #pragma unroll
    for (int k0 = 0; k0 < K; k0 += 32) {
        __syncthreads();                       // previous iter's LDS reads done
        async16(Ab + k0 + ga0, lA0);
        async16(Ab + k0 + ga1, lA1);
        async16(Bb + k0 + ga0, lB0);
        async16(Bb + k0 + ga1, lB1);
        __syncthreads();                       // implicit vmcnt(0) drains global_load_lds
        bf16x8 a[4], b[4];
        #pragma unroll
        for (int i = 0; i < 4; ++i) {
            a[i] = *(const bf16x8*)&As[(wm + i * 16 + l16) * 32 + q * 8];
            b[i] = *(const bf16x8*)&Bs[(wn + i * 16 + l16) * 32 + q * 8];
        }
        #pragma unroll
        for (int i = 0; i < 4; ++i)
            #pragma unroll
            for (int j = 0; j < 4; ++j)
                acc[i][j] = __builtin_amdgcn_mfma_f32_16x16x32_bf16(a[i], b[j], acc[i][j], 0, 0, 0);
    }

    // epilogue: D mapping col=l16, row=q*4+reg (verified)
    #pragma unroll
    for (int i = 0; i < 4; ++i) {
        int grow = row0 + wm + i * 16 + q * 4;
        #pragma unroll
        for (int j = 0; j < 4; ++j) {
            int gcol = col0 + wn + j * 16 + l16;
            ushort* p = Y + (size_t)grow * NW + gcol;
            #pragma unroll
            for (int r = 0; r < 4; ++r)
                p[(size_t)r * NW] = f2bf(acc[i][j][r]);
        }
    }
}

// ---------------- fused gather: out[d] = act( root + bias + accum + sum_r mean_r ) ----------------
// Thread owns (dst node, 8-col chunk); loops relation groups; no atomics.
template<int O>
__global__ __launch_bounds__(256)
void gather_kernel(const ushort* __restrict__ Y, int NW, int rel0, int nrel, int rootcol,
                   const int* __restrict__ row_ptr, const int* __restrict__ sorted_src,
                   const float* __restrict__ bias, const float* __restrict__ accum,
                   float* __restrict__ out_f32, ushort* __restrict__ out_bf16, int relu) {
    constexpr int TPN = O / 8;
    int d = blockIdx.x * (256 / TPN) + threadIdx.x / TPN;
    if (d >= N_NODES) return;
    int c0 = (threadIdx.x % TPN) * 8;
    float sum[8] = {};
    if (rootcol >= 0) {
        add8(sum, *(const uint4*)(Y + (size_t)d * NW + rootcol + c0));
        #pragma unroll
        for (int k = 0; k < 8; ++k) sum[k] += bias[c0 + k];
    }
    if (accum) {
        const float* ap = accum + (size_t)d * O + c0;
        float4 x0 = *(const float4*)ap, x1 = *(const float4*)(ap + 4);
        sum[0] += x0.x; sum[1] += x0.y; sum[2] += x0.z; sum[3] += x0.w;
        sum[4] += x1.x; sum[5] += x1.y; sum[6] += x1.z; sum[7] += x1.w;
    }
    for (int rr = 0; rr < nrel; ++rr) {
        int base = (rel0 + rr) * N_NODES + d;
        int s0 = row_ptr[base], s1 = row_ptr[base + 1];
        if (s1 <= s0) continue;
        float ps[8] = {};
        const ushort* Yc = Y + rr * O + c0;
        for (int e = s0; e < s1; ++e)
            add8(ps, *(const uint4*)(Yc + (size_t)sorted_src[e] * NW));
        float inv = 1.0f / (float)(s1 - s0);
        #pragma unroll
        for (int k = 0; k < 8; ++k) sum[k] += ps[k] * inv;
    }
    if (relu) {
        #pragma unroll
        for (int k = 0; k < 8; ++k) sum[k] = fmaxf(sum[k], 0.0f);
    }
    if (out_bf16) {
        ushort o[8];
        #pragma unroll
        for (int k = 0; k < 8; ++k) o[k] = f2bf(sum[k]);
        *(uint4*)(out_bf16 + (size_t)d * O + c0) = *(const uint4*)o;
    }
    if (out_f32) {
        float* p = out_f32 + (size_t)d * O + c0;
        *(float4*)p = make_float4(sum[0], sum[1], sum[2], sum[3]);
        *(float4*)(p + 4) = make_float4(sum[4], sum[5], sum[6], sum[7]);
    }
}

// ---------------- host side ----------------

static void launch_gemm(int K, const ushort* A, const ushort* BT, ushort* Y, int NW,
                        hipStream_t st) {
    dim3 g(N_PAD / 128, NW / 128), b(256);
    if (K == 128) gemm_mfma<128><<<g, b, 0, st>>>(A, BT, Y, NW);
    else          gemm_mfma<256><<<g, b, 0, st>>>(A, BT, Y, NW);
}

static void launch_gather(int O, const ushort* Y, int NW, int rel0, int nrel, int rootcol,
                          const int* rp, const int* ss, const float* bias, const float* accum,
                          float* of, ushort* ob, int relu, hipStream_t st) {
    if (O == 256)
        gather_kernel<256><<<dim3((N_NODES + 7) / 8), 256, 0, st>>>(Y, NW, rel0, nrel, rootcol,
                                                                    rp, ss, bias, accum, of, ob, relu);
    else
        gather_kernel<64><<<dim3((N_NODES + 31) / 32), 256, 0, st>>>(Y, NW, rel0, nrel, rootcol,
                                                                     rp, ss, bias, accum, of, ob, relu);
}

extern "C" void kernel_launch(void* const* d_in, const int* in_sizes, int n_in,
                              void* d_out, int out_size, void* d_ws, size_t ws_size,
                              hipStream_t stream) {
    const float* x  = (const float*)d_in[0];
    const int*   ei = (const int*)d_in[1];
    const int*   et = (const int*)d_in[2];
    const float* W[4]    = {(const float*)d_in[3], (const float*)d_in[6], (const float*)d_in[9],  (const float*)d_in[12]};
    const float* RT[4]   = {(const float*)d_in[4], (const float*)d_in[7], (const float*)d_in[10], (const float*)d_in[13]};
    const float* BI[4]   = {(const float*)d_in[5], (const float*)d_in[8], (const float*)d_in[11], (const float*)d_in[14]};
    const int KS[4] = {128, 256, 256, 256};
    const int OS[4] = {256, 256, 256, 64};
    const int NP[4] = {2304, 2304, 2304, 640};   // packed+padded BT rows
    const int* src = ei;
    const int* dst = ei + N_EDGES;

    // ---- workspace carve-up ----
    char* ws = (char*)d_ws;
    size_t off = 0;
    auto take = [&](size_t bytes) -> char* {
        char* p = ws + off;
        off = (off + bytes + 255) & ~(size_t)255;
        return p;
    };
    int* cnt        = (int*)take((size_t)NSEG * 4);
    int* row_ptr    = (int*)take((size_t)(NSEG + 1) * 4);
    int* sums       = (int*)take(512 * 4);
    int* sorted_src = (int*)take((size_t)N_EDGES * 4);
    ushort* BT[4];
    for (int l = 0; l < 4; ++l) BT[l] = (ushort*)take((size_t)NP[l] * KS[l] * 2);
    ushort* hb = (ushort*)take((size_t)N_PAD * 256 * 2);

    const size_t planA_need = off + (size_t)N_PAD * 2304 * 2 + (1u << 20);
    const bool planA = ws_size >= planA_need;
    ushort* Yb; float* hf = nullptr;
    if (planA) {
        Yb = (ushort*)take((size_t)N_PAD * 2304 * 2);
    } else {
        hf = (float*)take((size_t)N_PAD * 256 * 4);
        Yb = (ushort*)take((size_t)N_PAD * 512 * 2);
    }

    // ---- edge preprocessing (once per call) ----
    hipMemsetAsync(cnt, 0, (size_t)NSEG * 4, stream);
    count_edges<<<(N_EDGES + 255) / 256, 256, 0, stream>>>(dst, et, cnt);
    scan_pass1<<<SCAN_NB, 256, 0, stream>>>(cnt, sums);
    scan_pass2<<<1, 512, 0, stream>>>(sums, SCAN_NB);
    scan_pass3<<<SCAN_NB, 256, 0, stream>>>(cnt, sums, row_ptr);
    place_edges<<<(N_EDGES + 255) / 256, 256, 0, stream>>>(src, dst, et, row_ptr, cnt, sorted_src);

    // ---- weight pack (once per call) ----
    for (int l = 0; l < 4; ++l) {
        int n = NP[l] * KS[l];
        convert_weights<<<(n + 255) / 256, 256, 0, stream>>>(W[l], RT[l], BT[l], KS[l], OS[l], NP[l]);
    }

    // ---- input to bf16 ----
    f32_to_bf16<<<(N_NODES * 128 / 4 + 255) / 256, 256, 0, stream>>>(x, hb, N_NODES * 128 / 4);

    // ---- 4 layers ----
    for (int l = 0; l < 4; ++l) {
        const int K = KS[l], O = OS[l];
        const bool last = (l == 3);
        float*  of = last ? (float*)d_out : nullptr;
        ushort* ob = last ? nullptr : hb;
        int relu = last ? 0 : 1;
        if (planA) {
            launch_gemm(K, hb, BT[l], Yb, NP[l], stream);
            launch_gather(O, Yb, NP[l], 0, N_REL, N_REL * O, row_ptr, sorted_src,
                          BI[l], nullptr, of, ob, relu, stream);
        } else {
            for (int b = 0; b < 4; ++b) {      // relation bands {0,1},{2,3},{4,5},{6,7}
                int wdt = 2 * O;               // 512 or 128
                launch_gemm(K, hb, BT[l] + (size_t)(b * 2 * O) * K, Yb, wdt, stream);
                launch_gather(O, Yb, wdt, b * 2, 2, -1, row_ptr, sorted_src,
                              nullptr, b ? hf : nullptr, hf, nullptr, 0, stream);
            }
            int wr = (O == 256) ? 256 : 128;   // root band (incl. zero pad for O=64)
            launch_gemm(K, hb, BT[l] + (size_t)(N_REL * O) * K, Yb, wr, stream);
            launch_gather(O, Yb, wr, 0, 0, 0, row_ptr, sorted_src,
                          BI[l], hf, of, ob, relu, stream);
        }
    }
}